// Round 1
// baseline (293.828 us; speedup 1.0000x reference)
//
#include <hip/hip_runtime.h>

// MVDR beamformer pipeline: STFT -> causal PSD -> Souden MVDR -> beamform -> iSTFT
// Sizes fixed by the reference problem.
static constexpr int NFFT = 4096;
static constexpr int HOP  = 1024;
static constexpr int NF   = 2049;   // rfft bins
static constexpr int NT   = 29;     // frames
static constexpr int NS   = 32768;  // samples per channel
static constexpr int NB   = 2;      // batch
static constexpr int NSrc = 2;      // sources
static constexpr int NC   = 4;      // channels
static constexpr int NBS  = NB * NSrc;

#define PI_F     3.14159265358979323846f
#define TWO_PI_F 6.28318530717958647692f

__device__ inline float2 cmul(float2 a, float2 b) {
    return make_float2(a.x * b.x - a.y * b.y, a.x * b.y + a.y * b.x);
}
// a * conj(b)
__device__ inline float2 cmulc(float2 a, float2 b) {
    return make_float2(a.x * b.x + a.y * b.y, a.y * b.x - a.x * b.y);
}

// ---------------------------------------------------------------------------
// In-LDS 4096-point complex FFT, four-step (64 x 64) decomposition.
// DIR = -1 forward (e^{-i...}), +1 inverse (e^{+i...}, unscaled).
// bufA holds input (natural order n = n1*64 + n2); result lands in bufA
// (natural order k = k1 + 64*k2). bufB is scratch. 256 threads.
// ---------------------------------------------------------------------------
template <int DIR>
__device__ inline void fft4096(float2* bufA, float2* bufB,
                               const float* c64, const float* s64, int tid) {
    // Stage 1: A[k1][n2] = sum_{n1} x[n1*64+n2] * W64^{n1*k1}, then * W4096^{n2*k1}
    #pragma unroll 1
    for (int j = 0; j < 16; ++j) {
        int o  = tid + 256 * j;
        int k1 = o >> 6;
        int n2 = o & 63;
        float ar = 0.f, ai = 0.f;
        #pragma unroll 8
        for (int n1 = 0; n1 < 64; ++n1) {
            float2 v = bufA[(n1 << 6) + n2];
            int   m  = (n1 * k1) & 63;
            float tc = c64[m];
            float ts = (DIR < 0) ? -s64[m] : s64[m];
            ar += v.x * tc - v.y * ts;
            ai += v.x * ts + v.y * tc;
        }
        int   mi = (n2 * k1) & 4095;
        float th = (float)mi * (TWO_PI_F / 4096.0f);
        float sv, cv;
        __sincosf(th, &sv, &cv);
        sv = (DIR < 0) ? -sv : sv;
        bufB[o] = make_float2(ar * cv - ai * sv, ar * sv + ai * cv);
    }
    __syncthreads();
    // Stage 2: X[k1 + 64*k2] = sum_{n2} B[k1][n2] * W64^{n2*k2}
    #pragma unroll 1
    for (int j = 0; j < 16; ++j) {
        int o  = tid + 256 * j;
        int k1 = o >> 6;
        int k2 = o & 63;
        float ar = 0.f, ai = 0.f;
        #pragma unroll 8
        for (int n2 = 0; n2 < 64; ++n2) {
            float2 v = bufB[(k1 << 6) + n2];  // wave-uniform -> LDS broadcast
            int   m  = (n2 * k2) & 63;
            float tc = c64[m];
            float ts = (DIR < 0) ? -s64[m] : s64[m];
            ar += v.x * tc - v.y * ts;
            ai += v.x * ts + v.y * tc;
        }
        bufA[k1 + (k2 << 6)] = make_float2(ar, ai);
    }
    __syncthreads();
}

// ---------------------------------------------------------------------------
// STFT: one block per frame. 232 x-frames then 464 s-frames.
// Window = sqrt(0.5 - 0.5cos(2 pi n / 4096)) = sin(pi n / 4096) exactly.
// ---------------------------------------------------------------------------
__global__ __launch_bounds__(256) void stft_kernel(
    const float* __restrict__ x, const float* __restrict__ s,
    float2* __restrict__ Xs, float2* __restrict__ Ss) {
    __shared__ float2 bufA[4096];
    __shared__ float2 bufB[4096];
    __shared__ float  c64[64], s64[64];
    int tid = threadIdx.x;
    if (tid < 64) {
        float th = (float)tid * (TWO_PI_F / 64.0f);
        __sincosf(th, &s64[tid], &c64[tid]);
    }
    int fid = blockIdx.x;
    const float* src;
    float2* dst;
    if (fid < NB * NC * NT) {  // 232 mixture frames
        int b = fid / (NC * NT);
        int r = fid % (NC * NT);
        int c = r / NT;
        int t = r % NT;
        src = x + (size_t)((b * NC + c) * NS + t * HOP);
        dst = Xs + (size_t)((b * NC + c) * NT + t) * NF;
    } else {                   // 464 source frames
        int g  = fid - NB * NC * NT;
        int bs = g / (NC * NT);
        int r  = g % (NC * NT);
        int c  = r / NT;
        int t  = r % NT;
        src = s + (size_t)((bs * NC + c) * NS + t * HOP);
        dst = Ss + (size_t)((bs * NC + c) * NT + t) * NF;
    }
    for (int j = tid; j < 4096; j += 256) {
        float w = __sinf((float)j * (PI_F / 4096.0f));
        bufA[j] = make_float2(src[j] * w, 0.0f);
    }
    __syncthreads();
    fft4096<-1>(bufA, bufB, c64, s64, tid);
    for (int f = tid; f < NF; f += 256) dst[f] = bufA[f];
}

// ---------------------------------------------------------------------------
// MVDR: one thread per (bs, t, f). Recompute causal PSD sums (t+1 steps),
// 4x4 complex Gauss-Jordan inverse (no pivot: HPD + eps*I), trace-normalize,
// beamform with conj(ws).
// ---------------------------------------------------------------------------
__global__ __launch_bounds__(256) void mvdr_kernel(
    const float2* __restrict__ Xs, const float2* __restrict__ Ss,
    float2* __restrict__ Es) {
    int idx = blockIdx.x * 256 + threadIdx.x;
    const int total = NBS * NT * NF;
    if (idx >= total) return;
    int f  = idx % NF;
    int r  = idx / NF;
    int t  = r % NT;
    int bs = r / NT;
    int b  = bs >> 1;  // bs = b*NSrc + s with NSrc=2

    float2 ps[4][4], pn[4][4];
    #pragma unroll
    for (int i = 0; i < 4; ++i)
        #pragma unroll
        for (int j = 0; j < 4; ++j) { ps[i][j] = make_float2(0.f, 0.f); pn[i][j] = make_float2(0.f, 0.f); }

    for (int tp = 0; tp <= t; ++tp) {
        float2 Sv[4], Nv[4];
        #pragma unroll
        for (int c = 0; c < 4; ++c) {
            float2 sv = Ss[(size_t)((bs * NC + c) * NT + tp) * NF + f];
            float2 xv = Xs[(size_t)((b * NC + c) * NT + tp) * NF + f];
            Sv[c] = sv;
            Nv[c] = make_float2(xv.x - sv.x, xv.y - sv.y);
        }
        #pragma unroll
        for (int i = 0; i < 4; ++i)
            #pragma unroll
            for (int j = 0; j < 4; ++j) {
                float2 a = cmulc(Sv[i], Sv[j]);
                ps[i][j].x += a.x; ps[i][j].y += a.y;
                float2 c2 = cmulc(Nv[i], Nv[j]);
                pn[i][j].x += c2.x; pn[i][j].y += c2.y;
            }
    }
    float ic = 1.0f / (float)(t + 1);
    #pragma unroll
    for (int i = 0; i < 4; ++i)
        #pragma unroll
        for (int j = 0; j < 4; ++j) {
            ps[i][j].x *= ic; ps[i][j].y *= ic;
            pn[i][j].x *= ic; pn[i][j].y *= ic;
        }

    float tr_n = pn[0][0].x + pn[1][1].x + pn[2][2].x + pn[3][3].x;
    float eps  = tr_n * 1e-7f + 1e-8f;
    #pragma unroll
    for (int i = 0; i < 4; ++i) pn[i][i].x += eps;

    // Gauss-Jordan: M = [pn | I] -> [I | inv(pn)]
    float2 M[4][8];
    #pragma unroll
    for (int i = 0; i < 4; ++i) {
        #pragma unroll
        for (int j = 0; j < 4; ++j) M[i][j] = pn[i][j];
        #pragma unroll
        for (int j = 0; j < 4; ++j) M[i][4 + j] = make_float2((i == j) ? 1.f : 0.f, 0.f);
    }
    #pragma unroll
    for (int col = 0; col < 4; ++col) {
        float2 piv = M[col][col];
        float  dd  = piv.x * piv.x + piv.y * piv.y;
        float  idd = 1.0f / dd;
        float2 pinv = make_float2(piv.x * idd, -piv.y * idd);
        #pragma unroll
        for (int j = 0; j < 8; ++j) M[col][j] = cmul(M[col][j], pinv);
        #pragma unroll
        for (int rr = 0; rr < 4; ++rr) {
            if (rr == col) continue;
            float2 fac = M[rr][col];
            #pragma unroll
            for (int j = 0; j < 8; ++j) {
                float2 d = cmul(fac, M[col][j]);
                M[rr][j].x -= d.x; M[rr][j].y -= d.y;
            }
        }
    }

    // num = inv(pn) @ ps
    float2 num[4][4];
    #pragma unroll
    for (int i = 0; i < 4; ++i)
        #pragma unroll
        for (int j = 0; j < 4; ++j) {
            float2 acc = make_float2(0.f, 0.f);
            #pragma unroll
            for (int k = 0; k < 4; ++k) {
                float2 d = cmul(M[i][4 + k], ps[k][j]);
                acc.x += d.x; acc.y += d.y;
            }
            num[i][j] = acc;
        }
    float2 tr = make_float2(num[0][0].x + num[1][1].x + num[2][2].x + num[3][3].x + 1e-8f,
                            num[0][0].y + num[1][1].y + num[2][2].y + num[3][3].y);
    float td  = tr.x * tr.x + tr.y * tr.y;
    float itd = 1.0f / td;
    float2 tinv = make_float2(tr.x * itd, -tr.y * itd);

    float2 Xt[4];
    #pragma unroll
    for (int c = 0; c < 4; ++c)
        Xt[c] = Xs[(size_t)((b * NC + c) * NT + t) * NF + f];

    // enh[bo] = sum_a conj(ws[a][bo]) * Xt[a],  ws = num * tinv
    #pragma unroll
    for (int bo = 0; bo < 4; ++bo) {
        float2 e = make_float2(0.f, 0.f);
        #pragma unroll
        for (int a = 0; a < 4; ++a) {
            float2 w = cmul(num[a][bo], tinv);
            float2 d = cmulc(Xt[a], w);  // Xt * conj(w)
            e.x += d.x; e.y += d.y;
        }
        Es[(size_t)((bs * NC + bo) * NT + t) * NF + f] = e;
    }
}

// ---------------------------------------------------------------------------
// iSTFT: one block per frame. Hermitian-extend 2049 bins, inverse FFT,
// scale 1/N, window, write frame to workspace (no atomics).
// ---------------------------------------------------------------------------
__global__ __launch_bounds__(256) void istft_kernel(
    const float2* __restrict__ Es, float* __restrict__ Fr) {
    __shared__ float2 bufA[4096];
    __shared__ float2 bufB[4096];
    __shared__ float  c64[64], s64[64];
    int tid = threadIdx.x;
    if (tid < 64) {
        float th = (float)tid * (TWO_PI_F / 64.0f);
        __sincosf(th, &s64[tid], &c64[tid]);
    }
    int fid = blockIdx.x;  // 0..463 over (bs, c, t)
    int bs = fid / (NC * NT);
    int r  = fid % (NC * NT);
    int c  = r / NT;
    int t  = r % NT;
    const float2* src = Es + (size_t)((bs * NC + c) * NT + t) * NF;
    for (int f = tid; f < NF; f += 256) {
        float2 v = src[f];
        bufA[f] = v;
        if (f >= 1 && f < 2048) bufA[4096 - f] = make_float2(v.x, -v.y);
    }
    __syncthreads();
    fft4096<1>(bufA, bufB, c64, s64, tid);
    float* dst = Fr + (size_t)((bs * NC + c) * NT + t) * NFFT;
    for (int j = tid; j < 4096; j += 256) {
        float w = __sinf((float)j * (PI_F / 4096.0f));
        dst[j] = bufA[j].x * (1.0f / 4096.0f) * w;
    }
}

// ---------------------------------------------------------------------------
// Overlap-add + window-squared normalization. One thread per output sample.
// ---------------------------------------------------------------------------
__global__ __launch_bounds__(256) void ola_kernel(
    const float* __restrict__ Fr, float* __restrict__ out) {
    int idx = blockIdx.x * 256 + threadIdx.x;
    const int total = NBS * NC * NS;
    if (idx >= total) return;
    int p  = idx & (NS - 1);
    int ch = idx >> 15;  // bs*NC + c
    int t1 = p >> 10;
    if (t1 > NT - 1) t1 = NT - 1;
    int t0 = (p >= NFFT) ? ((p - (NFFT - 1) + (HOP - 1)) >> 10) : 0;
    float acc = 0.f, wacc = 0.f;
    for (int t = t0; t <= t1; ++t) {
        int   j = p - (t << 10);
        float w = __sinf((float)j * (PI_F / 4096.0f));
        acc  += Fr[((size_t)(ch * NT + t) << 12) + j];
        wacc += w * w;
    }
    out[idx] = acc / fmaxf(wacc, 1e-8f);
}

// ---------------------------------------------------------------------------
extern "C" void kernel_launch(void* const* d_in, const int* in_sizes, int n_in,
                              void* d_out, int out_size, void* d_ws, size_t ws_size,
                              hipStream_t stream) {
    const float* x = (const float*)d_in[0];  // (2,4,32768)
    const float* s = (const float*)d_in[1];  // (2,2,4,32768)
    float* out = (float*)d_out;              // (2,2,4,32768)

    // Workspace layout (26.6 MB):
    const size_t XS_N = (size_t)NB  * NC * NT * NF;  // 475,368 float2
    const size_t SS_N = (size_t)NBS * NC * NT * NF;  // 950,736 float2
    float2* Xs = (float2*)d_ws;
    float2* Ss = Xs + XS_N;
    float2* Es = Ss + SS_N;
    float*  Fr = (float*)(Es + SS_N);                // 1,900,544 float

    stft_kernel<<<NB * NC * NT + NBS * NC * NT, 256, 0, stream>>>(x, s, Xs, Ss);

    int mvdr_total = NBS * NT * NF;  // 237,684
    mvdr_kernel<<<(mvdr_total + 255) / 256, 256, 0, stream>>>(Xs, Ss, Es);

    istft_kernel<<<NBS * NC * NT, 256, 0, stream>>>(Es, Fr);

    int ola_total = NBS * NC * NS;   // 524,288
    ola_kernel<<<(ola_total + 255) / 256, 256, 0, stream>>>(Fr, out);
}

// Round 2
// 68.949 us; speedup vs baseline: 4.2615x; 4.2615x over previous
//
#include <hip/hip_runtime.h>

// MVDR beamformer pipeline: STFT -> causal PSD -> Souden MVDR -> beamform -> iSTFT
static constexpr int NFFT = 4096;
static constexpr int HOP  = 1024;
static constexpr int NF   = 2049;   // rfft bins
static constexpr int NT   = 29;     // frames
static constexpr int NS   = 32768;  // samples per channel
static constexpr int NB   = 2;      // batch
static constexpr int NSrc = 2;      // sources
static constexpr int NC   = 4;      // channels
static constexpr int NBS  = NB * NSrc;

#define PI_F     3.14159265358979323846f
#define TWO_PI_F 6.28318530717958647692f

// LDS padding: one extra float every 16 -> breaks all power-of-2 stride conflicts
#define IDX(a) ((a) + ((a) >> 4))
static constexpr int LDSN = 2048 + 128;  // padded length

__device__ inline float2 cmul(float2 a, float2 b) {
    return make_float2(a.x * b.x - a.y * b.y, a.x * b.y + a.y * b.x);
}
// a * conj(b)
__device__ inline float2 cmulc(float2 a, float2 b) {
    return make_float2(a.x * b.x + a.y * b.y, a.y * b.x - a.x * b.y);
}

// ---------------------------------------------------------------------------
// 4- and 8-point DFT building blocks. DIR=-1 forward (e^{-i}), +1 inverse.
// ---------------------------------------------------------------------------
template <int DIR>
__device__ inline void fft4v(float2 v[4]) {
    float2 t0 = make_float2(v[0].x + v[2].x, v[0].y + v[2].y);
    float2 t1 = make_float2(v[0].x - v[2].x, v[0].y - v[2].y);
    float2 t2 = make_float2(v[1].x + v[3].x, v[1].y + v[3].y);
    float2 t3 = make_float2(v[1].x - v[3].x, v[1].y - v[3].y);
    v[0] = make_float2(t0.x + t2.x, t0.y + t2.y);
    v[2] = make_float2(t0.x - t2.x, t0.y - t2.y);
    if (DIR < 0) {
        v[1] = make_float2(t1.x + t3.y, t1.y - t3.x);
        v[3] = make_float2(t1.x - t3.y, t1.y + t3.x);
    } else {
        v[1] = make_float2(t1.x - t3.y, t1.y + t3.x);
        v[3] = make_float2(t1.x + t3.y, t1.y - t3.x);
    }
}

template <int DIR>
__device__ inline void fft8v(float2 v[8]) {
    float2 e[4] = { v[0], v[2], v[4], v[6] };
    float2 o[4] = { v[1], v[3], v[5], v[7] };
    fft4v<DIR>(e);
    fft4v<DIR>(o);
    const float c = 0.70710678118654752f;
    float2 o0 = o[0], o1, o2, o3;
    if (DIR < 0) {
        o1 = make_float2(c * (o[1].x + o[1].y), c * (o[1].y - o[1].x));
        o2 = make_float2(o[2].y, -o[2].x);
        o3 = make_float2(c * (o[3].y - o[3].x), -c * (o[3].x + o[3].y));
    } else {
        o1 = make_float2(c * (o[1].x - o[1].y), c * (o[1].y + o[1].x));
        o2 = make_float2(-o[2].y, o[2].x);
        o3 = make_float2(-c * (o[3].x + o[3].y), c * (o[3].x - o[3].y));
    }
    v[0] = make_float2(e[0].x + o0.x, e[0].y + o0.y);
    v[4] = make_float2(e[0].x - o0.x, e[0].y - o0.y);
    v[1] = make_float2(e[1].x + o1.x, e[1].y + o1.y);
    v[5] = make_float2(e[1].x - o1.x, e[1].y - o1.y);
    v[2] = make_float2(e[2].x + o2.x, e[2].y + o2.y);
    v[6] = make_float2(e[2].x - o2.x, e[2].y - o2.y);
    v[3] = make_float2(e[3].x + o3.x, e[3].y + o3.y);
    v[7] = make_float2(e[3].x - o3.x, e[3].y - o3.y);
}

// ---------------------------------------------------------------------------
// Stockham radix-8 stage: src -> dst, 256 threads, one butterfly each.
// v[r] = src[j + r*256] * cis(DIR*2pi*(j%NS)*r/(NS*8)); fft8;
// dst[(j/NS)*NS*8 + j%NS + r*NS] = v[r].
// ---------------------------------------------------------------------------
template <int DIR, int NS>
__device__ inline void stage8(const float* __restrict__ reS, const float* __restrict__ imS,
                              float* __restrict__ reD, float* __restrict__ imD, int tid) {
    int j = tid;
    float2 v[8];
    #pragma unroll
    for (int r = 0; r < 8; ++r) {
        int a = IDX(j + (r << 8));
        v[r] = make_float2(reS[a], imS[a]);
    }
    if (NS > 1) {
        float ang = (float)DIR * (TWO_PI_F / (8.0f * (float)NS)) * (float)(j & (NS - 1));
        float2 w1; __sincosf(ang, &w1.y, &w1.x);
        float2 w = w1;
        v[1] = cmul(v[1], w);
        #pragma unroll
        for (int r = 2; r < 8; ++r) { w = cmul(w, w1); v[r] = cmul(v[r], w); }
    }
    fft8v<DIR>(v);
    int idxD = ((j & ~(NS - 1)) << 3) + (j & (NS - 1));
    #pragma unroll
    for (int r = 0; r < 8; ++r) {
        int a = IDX(idxD + r * NS);
        reD[a] = v[r].x;
        imD[a] = v[r].y;
    }
}

// Final radix-4 stage, NS=512: threads handle j = tid and tid+256. In natural order.
template <int DIR>
__device__ inline void stage4_512(const float* __restrict__ reS, const float* __restrict__ imS,
                                  float* __restrict__ reD, float* __restrict__ imD, int tid) {
    #pragma unroll
    for (int h = 0; h < 2; ++h) {
        int j = tid + (h << 8);
        float2 v[4];
        #pragma unroll
        for (int r = 0; r < 4; ++r) {
            int a = IDX(j + (r << 9));
            v[r] = make_float2(reS[a], imS[a]);
        }
        float ang = (float)DIR * (TWO_PI_F / 2048.0f) * (float)j;
        float2 w1; __sincosf(ang, &w1.y, &w1.x);
        float2 w2 = cmul(w1, w1);
        float2 w3 = cmul(w2, w1);
        v[1] = cmul(v[1], w1);
        v[2] = cmul(v[2], w2);
        v[3] = cmul(v[3], w3);
        fft4v<DIR>(v);
        #pragma unroll
        for (int r = 0; r < 4; ++r) {
            int a = IDX(j + (r << 9));
            reD[a] = v[r].x;
            imD[a] = v[r].y;
        }
    }
}

// 2048-pt complex FFT (Stockham 8,8,8,4). In/out in (reA,imA), natural order.
// Caller must __syncthreads() after filling A.
template <int DIR>
__device__ inline void fft2048(float* reA, float* imA, float* reB, float* imB, int tid) {
    stage8<DIR, 1>(reA, imA, reB, imB, tid);  __syncthreads();
    stage8<DIR, 8>(reB, imB, reA, imA, tid);  __syncthreads();
    stage8<DIR, 64>(reA, imA, reB, imB, tid); __syncthreads();
    stage4_512<DIR>(reB, imB, reA, imA, tid); __syncthreads();
}

// ---------------------------------------------------------------------------
// STFT: one block per frame (696 total). Real-packing: z[n]=x[2n]w+i x[2n+1]w,
// 2048-pt FFT, unpack to 2049 bins. Window w[j]=sin(pi j/4096).
// ---------------------------------------------------------------------------
__global__ __launch_bounds__(256) void stft_kernel(
    const float* __restrict__ x, const float* __restrict__ s,
    float2* __restrict__ Xs, float2* __restrict__ Ss) {
    __shared__ float reA[LDSN], imA[LDSN], reB[LDSN], imB[LDSN];
    int tid = threadIdx.x;
    int fid = blockIdx.x;
    const float* src;
    float2* dst;
    if (fid < NB * NC * NT) {
        int b = fid / (NC * NT);
        int r = fid % (NC * NT);
        int c = r / NT;
        int t = r % NT;
        src = x + (size_t)((b * NC + c) * NS + t * HOP);
        dst = Xs + (size_t)((b * NC + c) * NT + t) * NF;
    } else {
        int g  = fid - NB * NC * NT;
        int bs = g / (NC * NT);
        int r  = g % (NC * NT);
        int c  = r / NT;
        int t  = r % NT;
        src = s + (size_t)((bs * NC + c) * NS + t * HOP);
        dst = Ss + (size_t)((bs * NC + c) * NT + t) * NF;
    }
    const float2* s2 = (const float2*)src;
    for (int n = tid; n < 2048; n += 256) {
        float2 v = s2[n];
        float we = __sinf((float)n * (PI_F / 2048.0f));
        float wo = __sinf((float)(2 * n + 1) * (PI_F / 4096.0f));
        int a = IDX(n);
        reA[a] = v.x * we;
        imA[a] = v.y * wo;
    }
    __syncthreads();
    fft2048<-1>(reA, imA, reB, imB, tid);
    // unpack: X[k] = Ze + W^k Zo, X[2048-k] = conj(Ze - W^k Zo), W = e^{-i pi/2048}
    for (int k = tid; k <= 1024; k += 256) {
        int a1 = IDX(k);
        int a2 = IDX((2048 - k) & 2047);
        float2 Za = make_float2(reA[a1], imA[a1]);
        float2 Zb = make_float2(reA[a2], imA[a2]);
        if (k == 0) {
            dst[0]    = make_float2(Za.x + Za.y, 0.f);
            dst[2048] = make_float2(Za.x - Za.y, 0.f);
        } else {
            float2 Ze = make_float2(0.5f * (Za.x + Zb.x),  0.5f * (Za.y - Zb.y));
            float2 Zo = make_float2(0.5f * (Za.y + Zb.y), -0.5f * (Za.x - Zb.x));
            float ang = -(PI_F / 2048.0f) * (float)k;
            float2 W; __sincosf(ang, &W.y, &W.x);
            float2 WZo = cmul(W, Zo);
            dst[k] = make_float2(Ze.x + WZo.x, Ze.y + WZo.y);
            if (k < 1024)
                dst[2048 - k] = make_float2(Ze.x - WZo.x, -(Ze.y - WZo.y));
        }
    }
}

// ---------------------------------------------------------------------------
// MVDR: one thread per (bs, t, f). Recompute causal PSD sums, 4x4 complex
// Gauss-Jordan inverse (HPD + eps*I, no pivot), trace-normalize, beamform.
// ---------------------------------------------------------------------------
__global__ __launch_bounds__(256) void mvdr_kernel(
    const float2* __restrict__ Xs, const float2* __restrict__ Ss,
    float2* __restrict__ Es) {
    int idx = blockIdx.x * 256 + threadIdx.x;
    const int total = NBS * NT * NF;
    if (idx >= total) return;
    int f  = idx % NF;
    int r  = idx / NF;
    int t  = r % NT;
    int bs = r / NT;
    int b  = bs >> 1;

    float2 ps[4][4], pn[4][4];
    #pragma unroll
    for (int i = 0; i < 4; ++i)
        #pragma unroll
        for (int j = 0; j < 4; ++j) { ps[i][j] = make_float2(0.f, 0.f); pn[i][j] = make_float2(0.f, 0.f); }

    for (int tp = 0; tp <= t; ++tp) {
        float2 Sv[4], Nv[4];
        #pragma unroll
        for (int c = 0; c < 4; ++c) {
            float2 sv = Ss[(size_t)((bs * NC + c) * NT + tp) * NF + f];
            float2 xv = Xs[(size_t)((b * NC + c) * NT + tp) * NF + f];
            Sv[c] = sv;
            Nv[c] = make_float2(xv.x - sv.x, xv.y - sv.y);
        }
        #pragma unroll
        for (int i = 0; i < 4; ++i)
            #pragma unroll
            for (int j = 0; j < 4; ++j) {
                float2 a = cmulc(Sv[i], Sv[j]);
                ps[i][j].x += a.x; ps[i][j].y += a.y;
                float2 c2 = cmulc(Nv[i], Nv[j]);
                pn[i][j].x += c2.x; pn[i][j].y += c2.y;
            }
    }
    float ic = 1.0f / (float)(t + 1);
    #pragma unroll
    for (int i = 0; i < 4; ++i)
        #pragma unroll
        for (int j = 0; j < 4; ++j) {
            ps[i][j].x *= ic; ps[i][j].y *= ic;
            pn[i][j].x *= ic; pn[i][j].y *= ic;
        }

    float tr_n = pn[0][0].x + pn[1][1].x + pn[2][2].x + pn[3][3].x;
    float eps  = tr_n * 1e-7f + 1e-8f;
    #pragma unroll
    for (int i = 0; i < 4; ++i) pn[i][i].x += eps;

    float2 M[4][8];
    #pragma unroll
    for (int i = 0; i < 4; ++i) {
        #pragma unroll
        for (int j = 0; j < 4; ++j) M[i][j] = pn[i][j];
        #pragma unroll
        for (int j = 0; j < 4; ++j) M[i][4 + j] = make_float2((i == j) ? 1.f : 0.f, 0.f);
    }
    #pragma unroll
    for (int col = 0; col < 4; ++col) {
        float2 piv = M[col][col];
        float  idd = 1.0f / (piv.x * piv.x + piv.y * piv.y);
        float2 pinv = make_float2(piv.x * idd, -piv.y * idd);
        #pragma unroll
        for (int j = 0; j < 8; ++j) M[col][j] = cmul(M[col][j], pinv);
        #pragma unroll
        for (int rr = 0; rr < 4; ++rr) {
            if (rr == col) continue;
            float2 fac = M[rr][col];
            #pragma unroll
            for (int j = 0; j < 8; ++j) {
                float2 d = cmul(fac, M[col][j]);
                M[rr][j].x -= d.x; M[rr][j].y -= d.y;
            }
        }
    }

    float2 num[4][4];
    #pragma unroll
    for (int i = 0; i < 4; ++i)
        #pragma unroll
        for (int j = 0; j < 4; ++j) {
            float2 acc = make_float2(0.f, 0.f);
            #pragma unroll
            for (int k = 0; k < 4; ++k) {
                float2 d = cmul(M[i][4 + k], ps[k][j]);
                acc.x += d.x; acc.y += d.y;
            }
            num[i][j] = acc;
        }
    float2 tr = make_float2(num[0][0].x + num[1][1].x + num[2][2].x + num[3][3].x + 1e-8f,
                            num[0][0].y + num[1][1].y + num[2][2].y + num[3][3].y);
    float itd = 1.0f / (tr.x * tr.x + tr.y * tr.y);
    float2 tinv = make_float2(tr.x * itd, -tr.y * itd);

    float2 Xt[4];
    #pragma unroll
    for (int c = 0; c < 4; ++c)
        Xt[c] = Xs[(size_t)((b * NC + c) * NT + t) * NF + f];

    #pragma unroll
    for (int bo = 0; bo < 4; ++bo) {
        float2 e = make_float2(0.f, 0.f);
        #pragma unroll
        for (int a = 0; a < 4; ++a) {
            float2 w = cmul(num[a][bo], tinv);
            float2 d = cmulc(Xt[a], w);
            e.x += d.x; e.y += d.y;
        }
        Es[(size_t)((bs * NC + bo) * NT + t) * NF + f] = e;
    }
}

// ---------------------------------------------------------------------------
// iSTFT: one block per frame (464). Build Z[k] from X bins (inverse of the
// real-packing unpack), inverse 2048-pt FFT, window+scale, write frame.
// ---------------------------------------------------------------------------
__global__ __launch_bounds__(256) void istft_kernel(
    const float2* __restrict__ Es, float* __restrict__ Fr) {
    __shared__ float reA[LDSN], imA[LDSN], reB[LDSN], imB[LDSN];
    int tid = threadIdx.x;
    int fid = blockIdx.x;
    int bs = fid / (NC * NT);
    int r  = fid % (NC * NT);
    int c  = r / NT;
    int t  = r % NT;
    const float2* src = Es + (size_t)((bs * NC + c) * NT + t) * NF;
    for (int k = tid; k <= 1024; k += 256) {
        float2 A = src[k];
        float2 B = src[2048 - k];
        float2 Ze = make_float2(0.5f * (A.x + B.x), 0.5f * (A.y - B.y));
        float2 D  = make_float2(0.5f * (A.x - B.x), 0.5f * (A.y + B.y));
        float ang = (PI_F / 2048.0f) * (float)k;
        float2 W; __sincosf(ang, &W.y, &W.x);
        float2 Zo = cmul(W, D);
        int a1 = IDX(k);
        reA[a1] = Ze.x - Zo.y;
        imA[a1] = Ze.y + Zo.x;
        if (k > 0 && k < 1024) {
            int a2 = IDX(2048 - k);
            reA[a2] = Ze.x + Zo.y;
            imA[a2] = -Ze.y + Zo.x;
        }
    }
    __syncthreads();
    fft2048<1>(reA, imA, reB, imB, tid);
    float2* d2 = (float2*)(Fr + (size_t)((bs * NC + c) * NT + t) * NFFT);
    for (int n = tid; n < 2048; n += 256) {
        int a = IDX(n);
        float we = __sinf((float)n * (PI_F / 2048.0f)) * (1.0f / 2048.0f);
        float wo = __sinf((float)(2 * n + 1) * (PI_F / 4096.0f)) * (1.0f / 2048.0f);
        d2[n] = make_float2(reA[a] * we, imA[a] * wo);
    }
}

// ---------------------------------------------------------------------------
// Overlap-add + window-squared normalization. One thread per output sample.
// ---------------------------------------------------------------------------
__global__ __launch_bounds__(256) void ola_kernel(
    const float* __restrict__ Fr, float* __restrict__ out) {
    int idx = blockIdx.x * 256 + threadIdx.x;
    const int total = NBS * NC * NS;
    if (idx >= total) return;
    int p  = idx & (NS - 1);
    int ch = idx >> 15;
    int t1 = p >> 10;
    if (t1 > NT - 1) t1 = NT - 1;
    int t0 = (p >= NFFT) ? ((p - (NFFT - 1) + (HOP - 1)) >> 10) : 0;
    float acc = 0.f, wacc = 0.f;
    for (int t = t0; t <= t1; ++t) {
        int   j = p - (t << 10);
        float w = __sinf((float)j * (PI_F / 4096.0f));
        acc  += Fr[((size_t)(ch * NT + t) << 12) + j];
        wacc += w * w;
    }
    out[idx] = acc / fmaxf(wacc, 1e-8f);
}

// ---------------------------------------------------------------------------
extern "C" void kernel_launch(void* const* d_in, const int* in_sizes, int n_in,
                              void* d_out, int out_size, void* d_ws, size_t ws_size,
                              hipStream_t stream) {
    const float* x = (const float*)d_in[0];  // (2,4,32768)
    const float* s = (const float*)d_in[1];  // (2,2,4,32768)
    float* out = (float*)d_out;              // (2,2,4,32768)

    const size_t XS_N = (size_t)NB  * NC * NT * NF;
    const size_t SS_N = (size_t)NBS * NC * NT * NF;
    float2* Xs = (float2*)d_ws;
    float2* Ss = Xs + XS_N;
    float2* Es = Ss + SS_N;
    float*  Fr = (float*)(Es + SS_N);

    stft_kernel<<<NB * NC * NT + NBS * NC * NT, 256, 0, stream>>>(x, s, Xs, Ss);

    int mvdr_total = NBS * NT * NF;
    mvdr_kernel<<<(mvdr_total + 255) / 256, 256, 0, stream>>>(Xs, Ss, Es);

    istft_kernel<<<NBS * NC * NT, 256, 0, stream>>>(Es, Fr);

    int ola_total = NBS * NC * NS;
    ola_kernel<<<(ola_total + 255) / 256, 256, 0, stream>>>(Fr, out);
}

// Round 3
// 59.803 us; speedup vs baseline: 4.9133x; 1.1529x over previous
//
#include <hip/hip_runtime.h>

// MVDR beamformer pipeline: STFT -> causal PSD -> Souden MVDR -> beamform -> iSTFT
static constexpr int NFFT = 4096;
static constexpr int HOP  = 1024;
static constexpr int NF   = 2049;   // rfft bins
static constexpr int NT   = 29;     // frames
static constexpr int NS   = 32768;  // samples per channel
static constexpr int NB   = 2;      // batch
static constexpr int NSrc = 2;      // sources
static constexpr int NC   = 4;      // channels
static constexpr int NBS  = NB * NSrc;
static constexpr int PSDN = NBS * NT * NF;  // elements per PSD plane

#define PI_F     3.14159265358979323846f
#define TWO_PI_F 6.28318530717958647692f

// LDS padding: one extra float every 16 -> breaks all power-of-2 stride conflicts
#define IDX(a) ((a) + ((a) >> 4))
static constexpr int LDSN = 2048 + 128;  // padded length

__device__ inline float2 cmul(float2 a, float2 b) {
    return make_float2(a.x * b.x - a.y * b.y, a.x * b.y + a.y * b.x);
}
// a * conj(b)
__device__ inline float2 cmulc(float2 a, float2 b) {
    return make_float2(a.x * b.x + a.y * b.y, a.y * b.x - a.x * b.y);
}

// ---------------------------------------------------------------------------
// 4- and 8-point DFT building blocks. DIR=-1 forward (e^{-i}), +1 inverse.
// ---------------------------------------------------------------------------
template <int DIR>
__device__ inline void fft4v(float2 v[4]) {
    float2 t0 = make_float2(v[0].x + v[2].x, v[0].y + v[2].y);
    float2 t1 = make_float2(v[0].x - v[2].x, v[0].y - v[2].y);
    float2 t2 = make_float2(v[1].x + v[3].x, v[1].y + v[3].y);
    float2 t3 = make_float2(v[1].x - v[3].x, v[1].y - v[3].y);
    v[0] = make_float2(t0.x + t2.x, t0.y + t2.y);
    v[2] = make_float2(t0.x - t2.x, t0.y - t2.y);
    if (DIR < 0) {
        v[1] = make_float2(t1.x + t3.y, t1.y - t3.x);
        v[3] = make_float2(t1.x - t3.y, t1.y + t3.x);
    } else {
        v[1] = make_float2(t1.x - t3.y, t1.y + t3.x);
        v[3] = make_float2(t1.x + t3.y, t1.y - t3.x);
    }
}

template <int DIR>
__device__ inline void fft8v(float2 v[8]) {
    float2 e[4] = { v[0], v[2], v[4], v[6] };
    float2 o[4] = { v[1], v[3], v[5], v[7] };
    fft4v<DIR>(e);
    fft4v<DIR>(o);
    const float c = 0.70710678118654752f;
    float2 o0 = o[0], o1, o2, o3;
    if (DIR < 0) {
        o1 = make_float2(c * (o[1].x + o[1].y), c * (o[1].y - o[1].x));
        o2 = make_float2(o[2].y, -o[2].x);
        o3 = make_float2(c * (o[3].y - o[3].x), -c * (o[3].x + o[3].y));
    } else {
        o1 = make_float2(c * (o[1].x - o[1].y), c * (o[1].y + o[1].x));
        o2 = make_float2(-o[2].y, o[2].x);
        o3 = make_float2(-c * (o[3].x + o[3].y), c * (o[3].x - o[3].y));
    }
    v[0] = make_float2(e[0].x + o0.x, e[0].y + o0.y);
    v[4] = make_float2(e[0].x - o0.x, e[0].y - o0.y);
    v[1] = make_float2(e[1].x + o1.x, e[1].y + o1.y);
    v[5] = make_float2(e[1].x - o1.x, e[1].y - o1.y);
    v[2] = make_float2(e[2].x + o2.x, e[2].y + o2.y);
    v[6] = make_float2(e[2].x - o2.x, e[2].y - o2.y);
    v[3] = make_float2(e[3].x + o3.x, e[3].y + o3.y);
    v[7] = make_float2(e[3].x - o3.x, e[3].y - o3.y);
}

// ---------------------------------------------------------------------------
// Stockham radix-8 stage: src -> dst, 256 threads, one butterfly each.
// ---------------------------------------------------------------------------
template <int DIR, int NSs>
__device__ inline void stage8(const float* __restrict__ reS, const float* __restrict__ imS,
                              float* __restrict__ reD, float* __restrict__ imD, int tid) {
    int j = tid;
    float2 v[8];
    #pragma unroll
    for (int r = 0; r < 8; ++r) {
        int a = IDX(j + (r << 8));
        v[r] = make_float2(reS[a], imS[a]);
    }
    if (NSs > 1) {
        float ang = (float)DIR * (TWO_PI_F / (8.0f * (float)NSs)) * (float)(j & (NSs - 1));
        float2 w1; __sincosf(ang, &w1.y, &w1.x);
        float2 w = w1;
        v[1] = cmul(v[1], w);
        #pragma unroll
        for (int r = 2; r < 8; ++r) { w = cmul(w, w1); v[r] = cmul(v[r], w); }
    }
    fft8v<DIR>(v);
    int idxD = ((j & ~(NSs - 1)) << 3) + (j & (NSs - 1));
    #pragma unroll
    for (int r = 0; r < 8; ++r) {
        int a = IDX(idxD + r * NSs);
        reD[a] = v[r].x;
        imD[a] = v[r].y;
    }
}

// Final radix-4 stage, NS=512: threads handle j = tid and tid+256. Natural order.
template <int DIR>
__device__ inline void stage4_512(const float* __restrict__ reS, const float* __restrict__ imS,
                                  float* __restrict__ reD, float* __restrict__ imD, int tid) {
    #pragma unroll
    for (int h = 0; h < 2; ++h) {
        int j = tid + (h << 8);
        float2 v[4];
        #pragma unroll
        for (int r = 0; r < 4; ++r) {
            int a = IDX(j + (r << 9));
            v[r] = make_float2(reS[a], imS[a]);
        }
        float ang = (float)DIR * (TWO_PI_F / 2048.0f) * (float)j;
        float2 w1; __sincosf(ang, &w1.y, &w1.x);
        float2 w2 = cmul(w1, w1);
        float2 w3 = cmul(w2, w1);
        v[1] = cmul(v[1], w1);
        v[2] = cmul(v[2], w2);
        v[3] = cmul(v[3], w3);
        fft4v<DIR>(v);
        #pragma unroll
        for (int r = 0; r < 4; ++r) {
            int a = IDX(j + (r << 9));
            reD[a] = v[r].x;
            imD[a] = v[r].y;
        }
    }
}

template <int DIR>
__device__ inline void fft2048(float* reA, float* imA, float* reB, float* imB, int tid) {
    stage8<DIR, 1>(reA, imA, reB, imB, tid);  __syncthreads();
    stage8<DIR, 8>(reB, imB, reA, imA, tid);  __syncthreads();
    stage8<DIR, 64>(reA, imA, reB, imB, tid); __syncthreads();
    stage4_512<DIR>(reB, imB, reA, imA, tid); __syncthreads();
}

// ---------------------------------------------------------------------------
// STFT: one block per frame (696 total). Real-packing + 2048-pt FFT + unpack.
// ---------------------------------------------------------------------------
__global__ __launch_bounds__(256) void stft_kernel(
    const float* __restrict__ x, const float* __restrict__ s,
    float2* __restrict__ Xs, float2* __restrict__ Ss) {
    __shared__ float reA[LDSN], imA[LDSN], reB[LDSN], imB[LDSN];
    int tid = threadIdx.x;
    int fid = blockIdx.x;
    const float* src;
    float2* dst;
    if (fid < NB * NC * NT) {
        int b = fid / (NC * NT);
        int r = fid % (NC * NT);
        int c = r / NT;
        int t = r % NT;
        src = x + (size_t)((b * NC + c) * NS + t * HOP);
        dst = Xs + (size_t)((b * NC + c) * NT + t) * NF;
    } else {
        int g  = fid - NB * NC * NT;
        int bs = g / (NC * NT);
        int r  = g % (NC * NT);
        int c  = r / NT;
        int t  = r % NT;
        src = s + (size_t)((bs * NC + c) * NS + t * HOP);
        dst = Ss + (size_t)((bs * NC + c) * NT + t) * NF;
    }
    const float2* s2 = (const float2*)src;
    for (int n = tid; n < 2048; n += 256) {
        float2 v = s2[n];
        float we = __sinf((float)n * (PI_F / 2048.0f));
        float wo = __sinf((float)(2 * n + 1) * (PI_F / 4096.0f));
        int a = IDX(n);
        reA[a] = v.x * we;
        imA[a] = v.y * wo;
    }
    __syncthreads();
    fft2048<-1>(reA, imA, reB, imB, tid);
    for (int k = tid; k <= 1024; k += 256) {
        int a1 = IDX(k);
        int a2 = IDX((2048 - k) & 2047);
        float2 Za = make_float2(reA[a1], imA[a1]);
        float2 Zb = make_float2(reA[a2], imA[a2]);
        if (k == 0) {
            dst[0]    = make_float2(Za.x + Za.y, 0.f);
            dst[2048] = make_float2(Za.x - Za.y, 0.f);
        } else {
            float2 Ze = make_float2(0.5f * (Za.x + Zb.x),  0.5f * (Za.y - Zb.y));
            float2 Zo = make_float2(0.5f * (Za.y + Zb.y), -0.5f * (Za.x - Zb.x));
            float ang = -(PI_F / 2048.0f) * (float)k;
            float2 W; __sincosf(ang, &W.y, &W.x);
            float2 WZo = cmul(W, Zo);
            dst[k] = make_float2(Ze.x + WZo.x, Ze.y + WZo.y);
            if (k < 1024)
                dst[2048 - k] = make_float2(Ze.x - WZo.x, -(Ze.y - WZo.y));
        }
    }
}

// ---------------------------------------------------------------------------
// PSD cumsum kernel: one thread per (bs, entry-task, f). 20 tasks cover the
// 10 unique Hermitian entries of psd_s (tasks 0-9) and psd_n (10-19).
// Writes UNNORMALIZED prefix sums into 32 planes PSD[slot][bs][t][f].
// Slots: ps diag c -> c; ps off-pair p -> 4+2p (re), 5+2p (im); pn at +16.
// ---------------------------------------------------------------------------
__global__ __launch_bounds__(256) void psd_kernel(
    const float2* __restrict__ Xs, const float2* __restrict__ Ss,
    float* __restrict__ PSD) {
    int idx = blockIdx.x * 256 + threadIdx.x;
    const int total = NBS * 20 * NF;
    if (idx >= total) return;
    int f    = idx % NF;
    int r    = idx / NF;
    int task = r % 20;
    int bs   = r / 20;
    int b    = bs >> 1;
    int isN  = (task >= 10) ? 1 : 0;
    int e    = task - isN * 10;
    float* outbase = PSD + (size_t)(bs * NT) * NF + f;
    if (e < 4) {  // diagonal (real)
        int c = e;
        const float2* Sp = Ss + (size_t)((bs * NC + c) * NT) * NF + f;
        const float2* Xp = Xs + (size_t)((b  * NC + c) * NT) * NF + f;
        float acc = 0.f;
        float* op = outbase + (size_t)(isN * 16 + c) * PSDN;
        for (int t = 0; t < NT; ++t) {
            float2 v = Sp[(size_t)t * NF];
            if (isN) { float2 xv = Xp[(size_t)t * NF]; v.x = xv.x - v.x; v.y = xv.y - v.y; }
            acc += v.x * v.x + v.y * v.y;
            op[(size_t)t * NF] = acc;
        }
    } else {      // off-diagonal pair p: (0,1),(0,2),(0,3),(1,2),(1,3),(2,3)
        int p = e - 4;
        int i = (p < 3) ? 0 : ((p < 5) ? 1 : 2);
        int j = (p < 3) ? (p + 1) : ((p < 5) ? (p - 1) : 3);
        const float2* Spi = Ss + (size_t)((bs * NC + i) * NT) * NF + f;
        const float2* Spj = Ss + (size_t)((bs * NC + j) * NT) * NF + f;
        const float2* Xpi = Xs + (size_t)((b  * NC + i) * NT) * NF + f;
        const float2* Xpj = Xs + (size_t)((b  * NC + j) * NT) * NF + f;
        float2 acc = make_float2(0.f, 0.f);
        float* opr = outbase + (size_t)(isN * 16 + 4 + 2 * p) * PSDN;
        float* opi = outbase + (size_t)(isN * 16 + 5 + 2 * p) * PSDN;
        for (int t = 0; t < NT; ++t) {
            float2 vi = Spi[(size_t)t * NF];
            float2 vj = Spj[(size_t)t * NF];
            if (isN) {
                float2 xi = Xpi[(size_t)t * NF];
                float2 xj = Xpj[(size_t)t * NF];
                vi.x = xi.x - vi.x; vi.y = xi.y - vi.y;
                vj.x = xj.x - vj.x; vj.y = xj.y - vj.y;
            }
            float2 d = cmulc(vi, vj);
            acc.x += d.x; acc.y += d.y;
            opr[(size_t)t * NF] = acc.x;
            opi[(size_t)t * NF] = acc.y;
        }
    }
}

// ---------------------------------------------------------------------------
// Solve kernel: one thread per (bs, t, f). Rebuild Hermitian ps/pn from the
// 32 PSD planes, normalize, eps-load, Gauss-Jordan inverse, trace-normalize,
// beamform with conj(ws).
// ---------------------------------------------------------------------------
__global__ __launch_bounds__(256) void solve_kernel(
    const float2* __restrict__ Xs, const float* __restrict__ PSD,
    float2* __restrict__ Es) {
    int idx = blockIdx.x * 256 + threadIdx.x;
    const int total = NBS * NT * NF;
    if (idx >= total) return;
    int f  = idx % NF;
    int r  = idx / NF;
    int t  = r % NT;
    int bs = r / NT;
    int b  = bs >> 1;

    const float* P = PSD + (size_t)(bs * NT + t) * NF + f;
    float ic = 1.0f / (float)(t + 1);

    float2 ps[4][4], pn[4][4];
    #pragma unroll
    for (int c = 0; c < 4; ++c) {
        ps[c][c] = make_float2(P[(size_t)c * PSDN] * ic, 0.f);
        pn[c][c] = make_float2(P[(size_t)(16 + c) * PSDN] * ic, 0.f);
    }
    constexpr int PI6[6] = {0, 0, 0, 1, 1, 2};
    constexpr int PJ6[6] = {1, 2, 3, 2, 3, 3};
    #pragma unroll
    for (int p = 0; p < 6; ++p) {
        int i = PI6[p], j = PJ6[p];
        float re = P[(size_t)(4 + 2 * p) * PSDN] * ic;
        float im = P[(size_t)(5 + 2 * p) * PSDN] * ic;
        ps[i][j] = make_float2(re, im);
        ps[j][i] = make_float2(re, -im);
        re = P[(size_t)(20 + 2 * p) * PSDN] * ic;
        im = P[(size_t)(21 + 2 * p) * PSDN] * ic;
        pn[i][j] = make_float2(re, im);
        pn[j][i] = make_float2(re, -im);
    }

    float tr_n = pn[0][0].x + pn[1][1].x + pn[2][2].x + pn[3][3].x;
    float eps  = tr_n * 1e-7f + 1e-8f;
    #pragma unroll
    for (int i = 0; i < 4; ++i) pn[i][i].x += eps;

    float2 M[4][8];
    #pragma unroll
    for (int i = 0; i < 4; ++i) {
        #pragma unroll
        for (int j = 0; j < 4; ++j) M[i][j] = pn[i][j];
        #pragma unroll
        for (int j = 0; j < 4; ++j) M[i][4 + j] = make_float2((i == j) ? 1.f : 0.f, 0.f);
    }
    #pragma unroll
    for (int col = 0; col < 4; ++col) {
        float2 piv = M[col][col];
        float  idd = 1.0f / (piv.x * piv.x + piv.y * piv.y);
        float2 pinv = make_float2(piv.x * idd, -piv.y * idd);
        #pragma unroll
        for (int j = 0; j < 8; ++j) M[col][j] = cmul(M[col][j], pinv);
        #pragma unroll
        for (int rr = 0; rr < 4; ++rr) {
            if (rr == col) continue;
            float2 fac = M[rr][col];
            #pragma unroll
            for (int j = 0; j < 8; ++j) {
                float2 d = cmul(fac, M[col][j]);
                M[rr][j].x -= d.x; M[rr][j].y -= d.y;
            }
        }
    }

    float2 num[4][4];
    #pragma unroll
    for (int i = 0; i < 4; ++i)
        #pragma unroll
        for (int j = 0; j < 4; ++j) {
            float2 acc = make_float2(0.f, 0.f);
            #pragma unroll
            for (int k = 0; k < 4; ++k) {
                float2 d = cmul(M[i][4 + k], ps[k][j]);
                acc.x += d.x; acc.y += d.y;
            }
            num[i][j] = acc;
        }
    float2 tr = make_float2(num[0][0].x + num[1][1].x + num[2][2].x + num[3][3].x + 1e-8f,
                            num[0][0].y + num[1][1].y + num[2][2].y + num[3][3].y);
    float itd = 1.0f / (tr.x * tr.x + tr.y * tr.y);
    float2 tinv = make_float2(tr.x * itd, -tr.y * itd);

    float2 Xt[4];
    #pragma unroll
    for (int c = 0; c < 4; ++c)
        Xt[c] = Xs[(size_t)((b * NC + c) * NT + t) * NF + f];

    #pragma unroll
    for (int bo = 0; bo < 4; ++bo) {
        float2 e = make_float2(0.f, 0.f);
        #pragma unroll
        for (int a = 0; a < 4; ++a) {
            float2 w = cmul(num[a][bo], tinv);
            float2 d = cmulc(Xt[a], w);
            e.x += d.x; e.y += d.y;
        }
        Es[(size_t)((bs * NC + bo) * NT + t) * NF + f] = e;
    }
}

// ---------------------------------------------------------------------------
// Fallback fused MVDR (used only if workspace is too small for PSD planes).
// ---------------------------------------------------------------------------
__global__ __launch_bounds__(256) void mvdr_kernel(
    const float2* __restrict__ Xs, const float2* __restrict__ Ss,
    float2* __restrict__ Es) {
    int idx = blockIdx.x * 256 + threadIdx.x;
    const int total = NBS * NT * NF;
    if (idx >= total) return;
    int f  = idx % NF;
    int r  = idx / NF;
    int t  = r % NT;
    int bs = r / NT;
    int b  = bs >> 1;

    float2 ps[4][4], pn[4][4];
    #pragma unroll
    for (int i = 0; i < 4; ++i)
        #pragma unroll
        for (int j = 0; j < 4; ++j) { ps[i][j] = make_float2(0.f, 0.f); pn[i][j] = make_float2(0.f, 0.f); }

    for (int tp = 0; tp <= t; ++tp) {
        float2 Sv[4], Nv[4];
        #pragma unroll
        for (int c = 0; c < 4; ++c) {
            float2 sv = Ss[(size_t)((bs * NC + c) * NT + tp) * NF + f];
            float2 xv = Xs[(size_t)((b * NC + c) * NT + tp) * NF + f];
            Sv[c] = sv;
            Nv[c] = make_float2(xv.x - sv.x, xv.y - sv.y);
        }
        #pragma unroll
        for (int i = 0; i < 4; ++i)
            #pragma unroll
            for (int j = 0; j < 4; ++j) {
                float2 a = cmulc(Sv[i], Sv[j]);
                ps[i][j].x += a.x; ps[i][j].y += a.y;
                float2 c2 = cmulc(Nv[i], Nv[j]);
                pn[i][j].x += c2.x; pn[i][j].y += c2.y;
            }
    }
    float ic = 1.0f / (float)(t + 1);
    #pragma unroll
    for (int i = 0; i < 4; ++i)
        #pragma unroll
        for (int j = 0; j < 4; ++j) {
            ps[i][j].x *= ic; ps[i][j].y *= ic;
            pn[i][j].x *= ic; pn[i][j].y *= ic;
        }

    float tr_n = pn[0][0].x + pn[1][1].x + pn[2][2].x + pn[3][3].x;
    float eps  = tr_n * 1e-7f + 1e-8f;
    #pragma unroll
    for (int i = 0; i < 4; ++i) pn[i][i].x += eps;

    float2 M[4][8];
    #pragma unroll
    for (int i = 0; i < 4; ++i) {
        #pragma unroll
        for (int j = 0; j < 4; ++j) M[i][j] = pn[i][j];
        #pragma unroll
        for (int j = 0; j < 4; ++j) M[i][4 + j] = make_float2((i == j) ? 1.f : 0.f, 0.f);
    }
    #pragma unroll
    for (int col = 0; col < 4; ++col) {
        float2 piv = M[col][col];
        float  idd = 1.0f / (piv.x * piv.x + piv.y * piv.y);
        float2 pinv = make_float2(piv.x * idd, -piv.y * idd);
        #pragma unroll
        for (int j = 0; j < 8; ++j) M[col][j] = cmul(M[col][j], pinv);
        #pragma unroll
        for (int rr = 0; rr < 4; ++rr) {
            if (rr == col) continue;
            float2 fac = M[rr][col];
            #pragma unroll
            for (int j = 0; j < 8; ++j) {
                float2 d = cmul(fac, M[col][j]);
                M[rr][j].x -= d.x; M[rr][j].y -= d.y;
            }
        }
    }

    float2 num[4][4];
    #pragma unroll
    for (int i = 0; i < 4; ++i)
        #pragma unroll
        for (int j = 0; j < 4; ++j) {
            float2 acc = make_float2(0.f, 0.f);
            #pragma unroll
            for (int k = 0; k < 4; ++k) {
                float2 d = cmul(M[i][4 + k], ps[k][j]);
                acc.x += d.x; acc.y += d.y;
            }
            num[i][j] = acc;
        }
    float2 tr = make_float2(num[0][0].x + num[1][1].x + num[2][2].x + num[3][3].x + 1e-8f,
                            num[0][0].y + num[1][1].y + num[2][2].y + num[3][3].y);
    float itd = 1.0f / (tr.x * tr.x + tr.y * tr.y);
    float2 tinv = make_float2(tr.x * itd, -tr.y * itd);

    float2 Xt[4];
    #pragma unroll
    for (int c = 0; c < 4; ++c)
        Xt[c] = Xs[(size_t)((b * NC + c) * NT + t) * NF + f];

    #pragma unroll
    for (int bo = 0; bo < 4; ++bo) {
        float2 e = make_float2(0.f, 0.f);
        #pragma unroll
        for (int a = 0; a < 4; ++a) {
            float2 w = cmul(num[a][bo], tinv);
            float2 d = cmulc(Xt[a], w);
            e.x += d.x; e.y += d.y;
        }
        Es[(size_t)((bs * NC + bo) * NT + t) * NF + f] = e;
    }
}

// ---------------------------------------------------------------------------
// iSTFT: one block per frame (464). Pack bins, inverse FFT, window, write.
// ---------------------------------------------------------------------------
__global__ __launch_bounds__(256) void istft_kernel(
    const float2* __restrict__ Es, float* __restrict__ Fr) {
    __shared__ float reA[LDSN], imA[LDSN], reB[LDSN], imB[LDSN];
    int tid = threadIdx.x;
    int fid = blockIdx.x;
    int bs = fid / (NC * NT);
    int r  = fid % (NC * NT);
    int c  = r / NT;
    int t  = r % NT;
    const float2* src = Es + (size_t)((bs * NC + c) * NT + t) * NF;
    for (int k = tid; k <= 1024; k += 256) {
        float2 A = src[k];
        float2 B = src[2048 - k];
        float2 Ze = make_float2(0.5f * (A.x + B.x), 0.5f * (A.y - B.y));
        float2 D  = make_float2(0.5f * (A.x - B.x), 0.5f * (A.y + B.y));
        float ang = (PI_F / 2048.0f) * (float)k;
        float2 W; __sincosf(ang, &W.y, &W.x);
        float2 Zo = cmul(W, D);
        int a1 = IDX(k);
        reA[a1] = Ze.x - Zo.y;
        imA[a1] = Ze.y + Zo.x;
        if (k > 0 && k < 1024) {
            int a2 = IDX(2048 - k);
            reA[a2] = Ze.x + Zo.y;
            imA[a2] = -Ze.y + Zo.x;
        }
    }
    __syncthreads();
    fft2048<1>(reA, imA, reB, imB, tid);
    float2* d2 = (float2*)(Fr + (size_t)((bs * NC + c) * NT + t) * NFFT);
    for (int n = tid; n < 2048; n += 256) {
        int a = IDX(n);
        float we = __sinf((float)n * (PI_F / 2048.0f)) * (1.0f / 2048.0f);
        float wo = __sinf((float)(2 * n + 1) * (PI_F / 4096.0f)) * (1.0f / 2048.0f);
        d2[n] = make_float2(reA[a] * we, imA[a] * wo);
    }
}

// ---------------------------------------------------------------------------
// Overlap-add + window-squared normalization. One thread per output sample.
// ---------------------------------------------------------------------------
__global__ __launch_bounds__(256) void ola_kernel(
    const float* __restrict__ Fr, float* __restrict__ out) {
    int idx = blockIdx.x * 256 + threadIdx.x;
    const int total = NBS * NC * NS;
    if (idx >= total) return;
    int p  = idx & (NS - 1);
    int ch = idx >> 15;
    int t1 = p >> 10;
    if (t1 > NT - 1) t1 = NT - 1;
    int t0 = (p >= NFFT) ? ((p - (NFFT - 1) + (HOP - 1)) >> 10) : 0;
    float acc = 0.f, wacc = 0.f;
    for (int t = t0; t <= t1; ++t) {
        int   j = p - (t << 10);
        float w = __sinf((float)j * (PI_F / 4096.0f));
        acc  += Fr[((size_t)(ch * NT + t) << 12) + j];
        wacc += w * w;
    }
    out[idx] = acc / fmaxf(wacc, 1e-8f);
}

// ---------------------------------------------------------------------------
extern "C" void kernel_launch(void* const* d_in, const int* in_sizes, int n_in,
                              void* d_out, int out_size, void* d_ws, size_t ws_size,
                              hipStream_t stream) {
    const float* x = (const float*)d_in[0];  // (2,4,32768)
    const float* s = (const float*)d_in[1];  // (2,2,4,32768)
    float* out = (float*)d_out;              // (2,2,4,32768)

    const size_t XS_N = (size_t)NB  * NC * NT * NF;  // float2
    const size_t SS_N = (size_t)NBS * NC * NT * NF;  // float2
    const size_t FR_N = (size_t)NBS * NC * NT * NFFT; // float
    float2* Xs = (float2*)d_ws;
    float2* Ss = Xs + XS_N;
    float2* Es = Ss + SS_N;
    float*  Fr = (float*)(Es + SS_N);
    float*  PSD = Fr + FR_N;                          // 32 planes of PSDN floats

    const size_t needed = (XS_N + 2 * SS_N) * sizeof(float2)
                        + (FR_N + (size_t)32 * PSDN) * sizeof(float);

    stft_kernel<<<NB * NC * NT + NBS * NC * NT, 256, 0, stream>>>(x, s, Xs, Ss);

    int solve_total = NBS * NT * NF;  // 237,684
    if (ws_size >= needed) {
        int psd_total = NBS * 20 * NF;  // 163,920
        psd_kernel<<<(psd_total + 255) / 256, 256, 0, stream>>>(Xs, Ss, PSD);
        solve_kernel<<<(solve_total + 255) / 256, 256, 0, stream>>>(Xs, PSD, Es);
    } else {
        mvdr_kernel<<<(solve_total + 255) / 256, 256, 0, stream>>>(Xs, Ss, Es);
    }

    istft_kernel<<<NBS * NC * NT, 256, 0, stream>>>(Es, Fr);

    int ola_total = NBS * NC * NS;   // 524,288
    ola_kernel<<<(ola_total + 255) / 256, 256, 0, stream>>>(Fr, out);
}

// Round 4
// 46.898 us; speedup vs baseline: 6.2652x; 1.2752x over previous
//
#include <hip/hip_runtime.h>

// MVDR beamformer pipeline: STFT -> causal PSD (in-register scan) -> Souden MVDR -> beamform -> iSTFT
static constexpr int NFFT = 4096;
static constexpr int HOP  = 1024;
static constexpr int NF   = 2049;   // rfft bins
static constexpr int NT   = 29;     // frames
static constexpr int NS   = 32768;  // samples per channel
static constexpr int NB   = 2;      // batch
static constexpr int NSrc = 2;      // sources
static constexpr int NC   = 4;      // channels
static constexpr int NBS  = NB * NSrc;
static constexpr int FCHUNKS = (NF + 7) / 8;  // 257 f-chunks of 8 per block

#define PI_F     3.14159265358979323846f
#define TWO_PI_F 6.28318530717958647692f

// LDS padding: one extra float every 16 -> breaks all power-of-2 stride conflicts
#define IDX(a) ((a) + ((a) >> 4))
static constexpr int LDSN = 2048 + 128;  // padded length

__device__ inline float2 cmul(float2 a, float2 b) {
    return make_float2(a.x * b.x - a.y * b.y, a.x * b.y + a.y * b.x);
}
// a * conj(b)
__device__ inline float2 cmulc(float2 a, float2 b) {
    return make_float2(a.x * b.x + a.y * b.y, a.y * b.x - a.x * b.y);
}

// ---------------------------------------------------------------------------
// 4- and 8-point DFT building blocks. DIR=-1 forward (e^{-i}), +1 inverse.
// ---------------------------------------------------------------------------
template <int DIR>
__device__ inline void fft4v(float2 v[4]) {
    float2 t0 = make_float2(v[0].x + v[2].x, v[0].y + v[2].y);
    float2 t1 = make_float2(v[0].x - v[2].x, v[0].y - v[2].y);
    float2 t2 = make_float2(v[1].x + v[3].x, v[1].y + v[3].y);
    float2 t3 = make_float2(v[1].x - v[3].x, v[1].y - v[3].y);
    v[0] = make_float2(t0.x + t2.x, t0.y + t2.y);
    v[2] = make_float2(t0.x - t2.x, t0.y - t2.y);
    if (DIR < 0) {
        v[1] = make_float2(t1.x + t3.y, t1.y - t3.x);
        v[3] = make_float2(t1.x - t3.y, t1.y + t3.x);
    } else {
        v[1] = make_float2(t1.x - t3.y, t1.y + t3.x);
        v[3] = make_float2(t1.x + t3.y, t1.y - t3.x);
    }
}

template <int DIR>
__device__ inline void fft8v(float2 v[8]) {
    float2 e[4] = { v[0], v[2], v[4], v[6] };
    float2 o[4] = { v[1], v[3], v[5], v[7] };
    fft4v<DIR>(e);
    fft4v<DIR>(o);
    const float c = 0.70710678118654752f;
    float2 o0 = o[0], o1, o2, o3;
    if (DIR < 0) {
        o1 = make_float2(c * (o[1].x + o[1].y), c * (o[1].y - o[1].x));
        o2 = make_float2(o[2].y, -o[2].x);
        o3 = make_float2(c * (o[3].y - o[3].x), -c * (o[3].x + o[3].y));
    } else {
        o1 = make_float2(c * (o[1].x - o[1].y), c * (o[1].y + o[1].x));
        o2 = make_float2(-o[2].y, o[2].x);
        o3 = make_float2(-c * (o[3].x + o[3].y), c * (o[3].x - o[3].y));
    }
    v[0] = make_float2(e[0].x + o0.x, e[0].y + o0.y);
    v[4] = make_float2(e[0].x - o0.x, e[0].y - o0.y);
    v[1] = make_float2(e[1].x + o1.x, e[1].y + o1.y);
    v[5] = make_float2(e[1].x - o1.x, e[1].y - o1.y);
    v[2] = make_float2(e[2].x + o2.x, e[2].y + o2.y);
    v[6] = make_float2(e[2].x - o2.x, e[2].y - o2.y);
    v[3] = make_float2(e[3].x + o3.x, e[3].y + o3.y);
    v[7] = make_float2(e[3].x - o3.x, e[3].y - o3.y);
}

// ---------------------------------------------------------------------------
// Stockham radix-8 stage: src -> dst, 256 threads, one butterfly each.
// ---------------------------------------------------------------------------
template <int DIR, int NSs>
__device__ inline void stage8(const float* __restrict__ reS, const float* __restrict__ imS,
                              float* __restrict__ reD, float* __restrict__ imD, int tid) {
    int j = tid;
    float2 v[8];
    #pragma unroll
    for (int r = 0; r < 8; ++r) {
        int a = IDX(j + (r << 8));
        v[r] = make_float2(reS[a], imS[a]);
    }
    if (NSs > 1) {
        float ang = (float)DIR * (TWO_PI_F / (8.0f * (float)NSs)) * (float)(j & (NSs - 1));
        float2 w1; __sincosf(ang, &w1.y, &w1.x);
        float2 w = w1;
        v[1] = cmul(v[1], w);
        #pragma unroll
        for (int r = 2; r < 8; ++r) { w = cmul(w, w1); v[r] = cmul(v[r], w); }
    }
    fft8v<DIR>(v);
    int idxD = ((j & ~(NSs - 1)) << 3) + (j & (NSs - 1));
    #pragma unroll
    for (int r = 0; r < 8; ++r) {
        int a = IDX(idxD + r * NSs);
        reD[a] = v[r].x;
        imD[a] = v[r].y;
    }
}

// Final radix-4 stage, NS=512: threads handle j = tid and tid+256. Natural order.
template <int DIR>
__device__ inline void stage4_512(const float* __restrict__ reS, const float* __restrict__ imS,
                                  float* __restrict__ reD, float* __restrict__ imD, int tid) {
    #pragma unroll
    for (int h = 0; h < 2; ++h) {
        int j = tid + (h << 8);
        float2 v[4];
        #pragma unroll
        for (int r = 0; r < 4; ++r) {
            int a = IDX(j + (r << 9));
            v[r] = make_float2(reS[a], imS[a]);
        }
        float ang = (float)DIR * (TWO_PI_F / 2048.0f) * (float)j;
        float2 w1; __sincosf(ang, &w1.y, &w1.x);
        float2 w2 = cmul(w1, w1);
        float2 w3 = cmul(w2, w1);
        v[1] = cmul(v[1], w1);
        v[2] = cmul(v[2], w2);
        v[3] = cmul(v[3], w3);
        fft4v<DIR>(v);
        #pragma unroll
        for (int r = 0; r < 4; ++r) {
            int a = IDX(j + (r << 9));
            reD[a] = v[r].x;
            imD[a] = v[r].y;
        }
    }
}

template <int DIR>
__device__ inline void fft2048(float* reA, float* imA, float* reB, float* imB, int tid) {
    stage8<DIR, 1>(reA, imA, reB, imB, tid);  __syncthreads();
    stage8<DIR, 8>(reB, imB, reA, imA, tid);  __syncthreads();
    stage8<DIR, 64>(reA, imA, reB, imB, tid); __syncthreads();
    stage4_512<DIR>(reB, imB, reA, imA, tid); __syncthreads();
}

// ---------------------------------------------------------------------------
// STFT: one block per frame (696 total). Real-packing + 2048-pt FFT + unpack.
// ---------------------------------------------------------------------------
__global__ __launch_bounds__(256) void stft_kernel(
    const float* __restrict__ x, const float* __restrict__ s,
    float2* __restrict__ Xs, float2* __restrict__ Ss) {
    __shared__ float reA[LDSN], imA[LDSN], reB[LDSN], imB[LDSN];
    int tid = threadIdx.x;
    int fid = blockIdx.x;
    const float* src;
    float2* dst;
    if (fid < NB * NC * NT) {
        int b = fid / (NC * NT);
        int r = fid % (NC * NT);
        int c = r / NT;
        int t = r % NT;
        src = x + (size_t)((b * NC + c) * NS + t * HOP);
        dst = Xs + (size_t)((b * NC + c) * NT + t) * NF;
    } else {
        int g  = fid - NB * NC * NT;
        int bs = g / (NC * NT);
        int r  = g % (NC * NT);
        int c  = r / NT;
        int t  = r % NT;
        src = s + (size_t)((bs * NC + c) * NS + t * HOP);
        dst = Ss + (size_t)((bs * NC + c) * NT + t) * NF;
    }
    const float2* s2 = (const float2*)src;
    for (int n = tid; n < 2048; n += 256) {
        float2 v = s2[n];
        float we = __sinf((float)n * (PI_F / 2048.0f));
        float wo = __sinf((float)(2 * n + 1) * (PI_F / 4096.0f));
        int a = IDX(n);
        reA[a] = v.x * we;
        imA[a] = v.y * wo;
    }
    __syncthreads();
    fft2048<-1>(reA, imA, reB, imB, tid);
    for (int k = tid; k <= 1024; k += 256) {
        int a1 = IDX(k);
        int a2 = IDX((2048 - k) & 2047);
        float2 Za = make_float2(reA[a1], imA[a1]);
        float2 Zb = make_float2(reA[a2], imA[a2]);
        if (k == 0) {
            dst[0]    = make_float2(Za.x + Za.y, 0.f);
            dst[2048] = make_float2(Za.x - Za.y, 0.f);
        } else {
            float2 Ze = make_float2(0.5f * (Za.x + Zb.x),  0.5f * (Za.y - Zb.y));
            float2 Zo = make_float2(0.5f * (Za.y + Zb.y), -0.5f * (Za.x - Zb.x));
            float ang = -(PI_F / 2048.0f) * (float)k;
            float2 W; __sincosf(ang, &W.y, &W.x);
            float2 WZo = cmul(W, Zo);
            dst[k] = make_float2(Ze.x + WZo.x, Ze.y + WZo.y);
            if (k < 1024)
                dst[2048 - k] = make_float2(Ze.x - WZo.x, -(Ze.y - WZo.y));
        }
    }
}

// ---------------------------------------------------------------------------
// Fused MVDR: one thread per (bs, f, t). lane = (fpair<<5)|t, so the causal
// PSD cumsum is a width-32 segmented inclusive shuffle-scan over 32 floats
// (16 unique Hermitian entries x {S,N}). Then normalize, eps-load, 4x4
// complex Gauss-Jordan inverse, trace-normalize, beamform with conj(ws).
// Grid: NBS * 257 blocks x 256 threads; 8 f per block.
// ---------------------------------------------------------------------------
__global__ __launch_bounds__(256) void mvdr2_kernel(
    const float2* __restrict__ Xs, const float2* __restrict__ Ss,
    float2* __restrict__ Es) {
    int tid   = threadIdx.x;
    int lane  = tid & 63;
    int wave  = tid >> 6;
    int t     = lane & 31;
    int fpair = lane >> 5;
    int blk   = blockIdx.x;
    int bs    = blk / FCHUNKS;
    int f     = (blk % FCHUNKS) * 8 + wave * 2 + fpair;
    int b     = bs >> 1;
    bool valid = (t < NT) && (f < NF);

    float2 Sv[4], Xv[4], Nv[4];
    #pragma unroll
    for (int c = 0; c < 4; ++c) {
        if (valid) {
            Sv[c] = Ss[(size_t)((bs * NC + c) * NT + t) * NF + f];
            Xv[c] = Xs[(size_t)((b  * NC + c) * NT + t) * NF + f];
        } else {
            Sv[c] = make_float2(0.f, 0.f);
            Xv[c] = make_float2(0.f, 0.f);
        }
        Nv[c] = make_float2(Xv[c].x - Sv[c].x, Xv[c].y - Sv[c].y);
    }

    // 32 scan values: [0..3] ps diag, [4..15] ps off re/im, [16..19] pn diag,
    // [20..31] pn off re/im. Pairs: (0,1),(0,2),(0,3),(1,2),(1,3),(2,3).
    float v[32];
    #pragma unroll
    for (int c = 0; c < 4; ++c) {
        v[c]      = Sv[c].x * Sv[c].x + Sv[c].y * Sv[c].y;
        v[16 + c] = Nv[c].x * Nv[c].x + Nv[c].y * Nv[c].y;
    }
    constexpr int PI6[6] = {0, 0, 0, 1, 1, 2};
    constexpr int PJ6[6] = {1, 2, 3, 2, 3, 3};
    #pragma unroll
    for (int p = 0; p < 6; ++p) {
        float2 d = cmulc(Sv[PI6[p]], Sv[PJ6[p]]);
        v[4 + 2 * p] = d.x; v[5 + 2 * p] = d.y;
        d = cmulc(Nv[PI6[p]], Nv[PJ6[p]]);
        v[20 + 2 * p] = d.x; v[21 + 2 * p] = d.y;
    }

    // Inclusive scan over t within each 32-lane segment.
    #pragma unroll
    for (int dlt = 1; dlt < 32; dlt <<= 1) {
        #pragma unroll
        for (int k = 0; k < 32; ++k) {
            float up = __shfl_up(v[k], (unsigned)dlt, 32);
            if (t >= dlt) v[k] += up;
        }
    }

    // Rebuild normalized Hermitian matrices.
    float ic = 1.0f / (float)(t + 1);
    float2 ps[4][4], pn[4][4];
    #pragma unroll
    for (int c = 0; c < 4; ++c) {
        ps[c][c] = make_float2(v[c] * ic, 0.f);
        pn[c][c] = make_float2(v[16 + c] * ic, 0.f);
    }
    #pragma unroll
    for (int p = 0; p < 6; ++p) {
        int i = PI6[p], j = PJ6[p];
        float re = v[4 + 2 * p] * ic, im = v[5 + 2 * p] * ic;
        ps[i][j] = make_float2(re, im);
        ps[j][i] = make_float2(re, -im);
        re = v[20 + 2 * p] * ic; im = v[21 + 2 * p] * ic;
        pn[i][j] = make_float2(re, im);
        pn[j][i] = make_float2(re, -im);
    }

    float tr_n = pn[0][0].x + pn[1][1].x + pn[2][2].x + pn[3][3].x;
    float eps  = tr_n * 1e-7f + 1e-8f;
    #pragma unroll
    for (int i = 0; i < 4; ++i) pn[i][i].x += eps;

    // Gauss-Jordan: [pn | I] -> [I | inv(pn)] (HPD, no pivoting needed).
    float2 M[4][8];
    #pragma unroll
    for (int i = 0; i < 4; ++i) {
        #pragma unroll
        for (int j = 0; j < 4; ++j) M[i][j] = pn[i][j];
        #pragma unroll
        for (int j = 0; j < 4; ++j) M[i][4 + j] = make_float2((i == j) ? 1.f : 0.f, 0.f);
    }
    #pragma unroll
    for (int col = 0; col < 4; ++col) {
        float2 piv = M[col][col];
        float  idd = 1.0f / (piv.x * piv.x + piv.y * piv.y);
        float2 pinv = make_float2(piv.x * idd, -piv.y * idd);
        #pragma unroll
        for (int j = 0; j < 8; ++j) M[col][j] = cmul(M[col][j], pinv);
        #pragma unroll
        for (int rr = 0; rr < 4; ++rr) {
            if (rr == col) continue;
            float2 fac = M[rr][col];
            #pragma unroll
            for (int j = 0; j < 8; ++j) {
                float2 d = cmul(fac, M[col][j]);
                M[rr][j].x -= d.x; M[rr][j].y -= d.y;
            }
        }
    }

    // num = inv(pn) @ ps
    float2 num[4][4];
    #pragma unroll
    for (int i = 0; i < 4; ++i)
        #pragma unroll
        for (int j = 0; j < 4; ++j) {
            float2 acc = make_float2(0.f, 0.f);
            #pragma unroll
            for (int k = 0; k < 4; ++k) {
                float2 d = cmul(M[i][4 + k], ps[k][j]);
                acc.x += d.x; acc.y += d.y;
            }
            num[i][j] = acc;
        }
    float2 tr = make_float2(num[0][0].x + num[1][1].x + num[2][2].x + num[3][3].x + 1e-8f,
                            num[0][0].y + num[1][1].y + num[2][2].y + num[3][3].y);
    float itd = 1.0f / (tr.x * tr.x + tr.y * tr.y);
    float2 tinv = make_float2(tr.x * itd, -tr.y * itd);

    #pragma unroll
    for (int bo = 0; bo < 4; ++bo) {
        float2 e = make_float2(0.f, 0.f);
        #pragma unroll
        for (int a = 0; a < 4; ++a) {
            float2 w = cmul(num[a][bo], tinv);
            float2 d = cmulc(Xv[a], w);  // X * conj(ws)
            e.x += d.x; e.y += d.y;
        }
        if (valid)
            Es[(size_t)((bs * NC + bo) * NT + t) * NF + f] = e;
    }
}

// ---------------------------------------------------------------------------
// iSTFT: one block per frame (464). Pack bins, inverse FFT, window, write.
// ---------------------------------------------------------------------------
__global__ __launch_bounds__(256) void istft_kernel(
    const float2* __restrict__ Es, float* __restrict__ Fr) {
    __shared__ float reA[LDSN], imA[LDSN], reB[LDSN], imB[LDSN];
    int tid = threadIdx.x;
    int fid = blockIdx.x;
    int bs = fid / (NC * NT);
    int r  = fid % (NC * NT);
    int c  = r / NT;
    int t  = r % NT;
    const float2* src = Es + (size_t)((bs * NC + c) * NT + t) * NF;
    for (int k = tid; k <= 1024; k += 256) {
        float2 A = src[k];
        float2 B = src[2048 - k];
        float2 Ze = make_float2(0.5f * (A.x + B.x), 0.5f * (A.y - B.y));
        float2 D  = make_float2(0.5f * (A.x - B.x), 0.5f * (A.y + B.y));
        float ang = (PI_F / 2048.0f) * (float)k;
        float2 W; __sincosf(ang, &W.y, &W.x);
        float2 Zo = cmul(W, D);
        int a1 = IDX(k);
        reA[a1] = Ze.x - Zo.y;
        imA[a1] = Ze.y + Zo.x;
        if (k > 0 && k < 1024) {
            int a2 = IDX(2048 - k);
            reA[a2] = Ze.x + Zo.y;
            imA[a2] = -Ze.y + Zo.x;
        }
    }
    __syncthreads();
    fft2048<1>(reA, imA, reB, imB, tid);
    float2* d2 = (float2*)(Fr + (size_t)((bs * NC + c) * NT + t) * NFFT);
    for (int n = tid; n < 2048; n += 256) {
        int a = IDX(n);
        float we = __sinf((float)n * (PI_F / 2048.0f)) * (1.0f / 2048.0f);
        float wo = __sinf((float)(2 * n + 1) * (PI_F / 4096.0f)) * (1.0f / 2048.0f);
        d2[n] = make_float2(reA[a] * we, imA[a] * wo);
    }
}

// ---------------------------------------------------------------------------
// Overlap-add + window-squared normalization. One thread per output sample.
// ---------------------------------------------------------------------------
__global__ __launch_bounds__(256) void ola_kernel(
    const float* __restrict__ Fr, float* __restrict__ out) {
    int idx = blockIdx.x * 256 + threadIdx.x;
    const int total = NBS * NC * NS;
    if (idx >= total) return;
    int p  = idx & (NS - 1);
    int ch = idx >> 15;
    int t1 = p >> 10;
    if (t1 > NT - 1) t1 = NT - 1;
    int t0 = (p >= NFFT) ? ((p - (NFFT - 1) + (HOP - 1)) >> 10) : 0;
    float acc = 0.f, wacc = 0.f;
    for (int t = t0; t <= t1; ++t) {
        int   j = p - (t << 10);
        float w = __sinf((float)j * (PI_F / 4096.0f));
        acc  += Fr[((size_t)(ch * NT + t) << 12) + j];
        wacc += w * w;
    }
    out[idx] = acc / fmaxf(wacc, 1e-8f);
}

// ---------------------------------------------------------------------------
extern "C" void kernel_launch(void* const* d_in, const int* in_sizes, int n_in,
                              void* d_out, int out_size, void* d_ws, size_t ws_size,
                              hipStream_t stream) {
    const float* x = (const float*)d_in[0];  // (2,4,32768)
    const float* s = (const float*)d_in[1];  // (2,2,4,32768)
    float* out = (float*)d_out;              // (2,2,4,32768)

    const size_t XS_N = (size_t)NB  * NC * NT * NF;   // float2
    const size_t SS_N = (size_t)NBS * NC * NT * NF;   // float2
    float2* Xs = (float2*)d_ws;
    float2* Ss = Xs + XS_N;
    float2* Es = Ss + SS_N;
    float*  Fr = (float*)(Es + SS_N);

    stft_kernel<<<NB * NC * NT + NBS * NC * NT, 256, 0, stream>>>(x, s, Xs, Ss);

    mvdr2_kernel<<<NBS * FCHUNKS, 256, 0, stream>>>(Xs, Ss, Es);

    istft_kernel<<<NBS * NC * NT, 256, 0, stream>>>(Es, Fr);

    int ola_total = NBS * NC * NS;   // 524,288
    ola_kernel<<<(ola_total + 255) / 256, 256, 0, stream>>>(Fr, out);
}